// Round 8
// baseline (380.505 us; speedup 1.0000x reference)
//
#include <hip/hip_runtime.h>

// Problem constants (fixed by setup_inputs)
constexpr int BB = 16;         // batch
constexpr int SS = 4096;       // seq
constexpr int DD = 1024;       // hidden dim
constexpr int KK = 65536;      // num keys
constexpr int GM = BB * SS;    // GEMM M = 65536
constexpr int GK = DD;         // GEMM K = 1024

typedef __attribute__((ext_vector_type(8))) short bf16x8;
typedef __attribute__((ext_vector_type(4))) float f32x4;
typedef __attribute__((ext_vector_type(8))) unsigned short ushort8;

#define GLD_LDS16(g, l)                                                        \
  __builtin_amdgcn_global_load_lds(                                            \
      (const __attribute__((address_space(1))) void*)(g),                      \
      (__attribute__((address_space(3))) void*)(l), 16, 0, 0)

__device__ __forceinline__ unsigned short f2bf(float x) {
  unsigned u = __float_as_uint(x);
  u += 0x7fffu + ((u >> 16) & 1u);   // RNE
  return (unsigned short)(u >> 16);
}

// ---------------- cvt body: one float8 chunk ---------------------------------
__device__ __forceinline__ void cvt_body(const float* __restrict__ in,
                                         unsigned short* __restrict__ out,
                                         int i) {
  const float4* p = (const float4*)in + (size_t)i * 2;
  float4 a = p[0], b = p[1];
  ushort8 r;
  r[0] = f2bf(a.x); r[1] = f2bf(a.y); r[2] = f2bf(a.z); r[3] = f2bf(a.w);
  r[4] = f2bf(b.x); r[5] = f2bf(b.y); r[6] = f2bf(b.z); r[7] = f2bf(b.w);
  *(ushort8*)(out + (size_t)i * 8) = r;
}

// ---------------- q split: csig -> bf16 hi + bf16 lo residual ---------------
__global__ __launch_bounds__(256) void qsplit(const float* __restrict__ csig,
                                              unsigned short* __restrict__ qh,
                                              unsigned short* __restrict__ ql) {
  int i = blockIdx.x * 256 + threadIdx.x;   // 64 blocks cover 16384
  float v = csig[i];
  unsigned short h = f2bf(v);
  float hf = __uint_as_float((unsigned)h << 16);
  qh[i] = h;
  ql[i] = f2bf(v - hf);
}

// ---------------- cos scores via split-bf16 MFMA (R7-proven inner loop) -----
// Wave handles 16 keys (cols), all 16 batches.  Lane (fr,kg): key = base+fr,
// reads 32B of its key row at d = t*32 + kg*8 (wave consumes 16 full 128B
// lines).  Keys split in-register to bf16 hi/lo; dot = qh*kh + ql*kh + qh*kl
// (3 MFMA, err ~2^-18 << top-2 gap ~0.0076).  Norm exact fp32.  No LDS.
__device__ __forceinline__ void cos_mfma_body(
    const float* __restrict__ keys, const unsigned short* __restrict__ qh,
    const unsigned short* __restrict__ ql, float* __restrict__ pscore,
    int* __restrict__ pidx, int cblk, int tid,
    float (*rs)[16], int (*ri)[16]) {
  int lane = tid & 63, w = tid >> 6;
  int fr = lane & 15, kg = lane >> 4;
  int key = cblk * 64 + w * 16 + fr;

  const float* krow = keys + (size_t)key * DD + kg * 8;
  const unsigned short* qhp = qh + fr * DD + kg * 8;
  const unsigned short* qlp = ql + fr * DD + kg * 8;

  f32x4 acc = {};
  float nrm = 0.f;

  float4 ka = *(const float4*)krow;
  float4 kb = *(const float4*)(krow + 4);
  bf16x8 h8 = *(const bf16x8*)qhp;
  bf16x8 l8 = *(const bf16x8*)qlp;

  for (int t = 0; t < 32; ++t) {
    float4 kc = ka, kd = kb;
    bf16x8 hh = h8, ll = l8;
    if (t + 1 < 32) {   // prefetch next chunk (T14)
      ka = *(const float4*)(krow + (t + 1) * 32);
      kb = *(const float4*)(krow + (t + 1) * 32 + 4);
      h8 = *(const bf16x8*)(qhp + (t + 1) * 32);
      l8 = *(const bf16x8*)(qlp + (t + 1) * 32);
    }
    float ke[8] = {kc.x, kc.y, kc.z, kc.w, kd.x, kd.y, kd.z, kd.w};
    ushort8 khv, klv;
#pragma unroll
    for (int j = 0; j < 8; ++j) {
      float v = ke[j];
      unsigned short h = f2bf(v);
      float hf = __uint_as_float((unsigned)h << 16);
      khv[j] = h;
      klv[j] = f2bf(v - hf);
      nrm = fmaf(v, v, nrm);
    }
    bf16x8 kh8 = *(bf16x8*)&khv, kl8 = *(bf16x8*)&klv;
    acc = __builtin_amdgcn_mfma_f32_16x16x32_bf16(hh, kh8, acc, 0, 0, 0);
    acc = __builtin_amdgcn_mfma_f32_16x16x32_bf16(ll, kh8, acc, 0, 0, 0);
    acc = __builtin_amdgcn_mfma_f32_16x16x32_bf16(hh, kl8, acc, 0, 0, 0);
  }

  // full ||k||^2: reduce across the 4 kg-lanes of this key
  nrm += __shfl_xor(nrm, 16);
  nrm += __shfl_xor(nrm, 32);
  float inv = rsqrtf(fmaxf(nrm, 1e-24f));

  // lane holds batches kg*4+j for its key; argmax over fr within wave
#pragma unroll
  for (int j = 0; j < 4; ++j) {
    float s = acc[j] * inv;
    int i = key;
#pragma unroll
    for (int off = 1; off < 16; off <<= 1) {
      float s2 = __shfl_xor(s, off);
      int i2 = __shfl_xor(i, off);
      if (s2 > s || (s2 == s && i2 < i)) { s = s2; i = i2; }
    }
    if (fr == 0) { rs[w][kg * 4 + j] = s; ri[w][kg * 4 + j] = i; }
  }
  __syncthreads();
  if (tid < 16) {
    float bs = rs[0][tid]; int bi = ri[0][tid];
#pragma unroll
    for (int w2 = 1; w2 < 4; ++w2) {
      float s = rs[w2][tid]; int i = ri[w2][tid];
      if (s > bs || (s == bs && i < bi)) { bs = s; bi = i; }
    }
    pscore[(size_t)tid * 1024 + cblk] = bs;
    pidx[(size_t)tid * 1024 + cblk] = bi;
  }
}

// ---------------- fused prep: cos + cvt(hidden) + cvt(W), role-striped ------
// 5632 blocks = 512 stripes x 11 (2 cos + 9 cvt) -> cos and cvt co-resident
// on every CU from dispatch start; cvt waves' loads hide cos's HBM latency.
__global__ __launch_bounds__(256) void fused_prep(
    const float* __restrict__ keys, const unsigned short* __restrict__ qh,
    const unsigned short* __restrict__ ql, float* __restrict__ pscore,
    int* __restrict__ pidx,
    const float* __restrict__ hidden, unsigned short* __restrict__ hbf,
    const float* __restrict__ W, unsigned short* __restrict__ wbf) {
  __shared__ float rs[4][16];
  __shared__ int ri[4][16];
  int bid = blockIdx.x, tid = threadIdx.x;
  int g = bid / 11, r = bid - g * 11;
  if (r < 2) {
    cos_mfma_body(keys, qh, ql, pscore, pidx, g * 2 + r, tid, rs, ri);
  } else {
    int v = g * 9 + (r - 2);         // 0..4607
    if (v < 4096) {
      // hidden: 8388608 chunks = 4096 v-slots x 256 thr x 8 rounds
      int base = v * 256 + tid;
#pragma unroll
      for (int q = 0; q < 8; ++q)
        cvt_body(hidden, hbf, base + q * (4096 * 256));
    } else {
      // W: 131072 chunks = 512 v-slots x 256 thr
      cvt_body(W, wbf, (v - 4096) * 256 + tid);
    }
  }
}

// =====================  GEMM: 256x256 tile, 8-phase (R3-proven) =============
// C[m,n] = sum_k A[m,k]*W[n,k] + bias[n].  BM=BN=256, BK=64, 8 waves (2Mx4N),
// LDS 128 KiB (2 buf x (A 32KB + B 32KB)).  K = 1024 -> 16 K-tiles, 8 iters.
// vmcnt(6) at ph4/ph8 forces next tile fully landed before its first read.
// LDS swizzle: short_idx ^= (row&7)<<3, applied as inverse-permuted GLOBAL
// source + swizzled ds_read (both-sides rule).

#define LDA8(AH, BUF) do {                                                     \
  _Pragma("unroll") for (int ms = 0; ms < 4; ++ms) {                           \
    int rowa = (wm << 7) + ((AH) << 6) + (ms << 4) + fr;                       \
    _Pragma("unroll") for (int ks = 0; ks < 2; ++ks) {                         \
      int ia = ((rowa << 6) + (ks << 5) + (kg << 3)) ^ sw;                     \
      ar[ms * 2 + ks] = *(const bf16x8*)&lds[(BUF) + ia]; } }                  \
} while (0)

#define LDB4(NP, BUF) do {                                                     \
  _Pragma("unroll") for (int nn = 0; nn < 2; ++nn) {                           \
    int rowb = (wn << 6) + ((((NP) << 1) + nn) << 4) + fr;                     \
    _Pragma("unroll") for (int ks = 0; ks < 2; ++ks) {                         \
      int ib = ((rowb << 6) + (ks << 5) + (kg << 3)) ^ sw;                     \
      br[(((NP) << 1) + nn) * 2 + ks] = *(const bf16x8*)&lds[(BUF) + ib]; } }  \
} while (0)

#define MFMAQ(AH, NP) do {                                                     \
  _Pragma("unroll") for (int ms = 0; ms < 4; ++ms)                             \
  _Pragma("unroll") for (int nn = 0; nn < 2; ++nn)                             \
  _Pragma("unroll") for (int ks = 0; ks < 2; ++ks)                             \
    acc[((AH) << 2) + ms][((NP) << 1) + nn] =                                  \
      __builtin_amdgcn_mfma_f32_16x16x32_bf16(ar[ms * 2 + ks],                 \
        br[(((NP) << 1) + nn) * 2 + ks],                                       \
        acc[((AH) << 2) + ms][((NP) << 1) + nn], 0, 0, 0);                     \
} while (0)

#define STAGEQ(GB, LB, QJ)                                                     \
  GLD_LDS16((GB) + (size_t)(((QJ) << 6) + srq) * GK + ssc,                     \
            &lds[(LB) + ((((QJ) << 9) + (wv << 6)) << 3)])

#define PH_MID do { __builtin_amdgcn_s_barrier();                              \
  asm volatile("s_waitcnt lgkmcnt(0)" ::: "memory");                           \
  __builtin_amdgcn_sched_barrier(0);                                           \
  __builtin_amdgcn_s_setprio(1); } while (0)

#define PH_END do { __builtin_amdgcn_s_setprio(0);                             \
  __builtin_amdgcn_s_barrier(); } while (0)

#define PH_END_V(N) do { __builtin_amdgcn_s_setprio(0);                        \
  asm volatile("s_waitcnt vmcnt(" #N ")" ::: "memory");                        \
  __builtin_amdgcn_sched_barrier(0);                                           \
  __builtin_amdgcn_s_barrier(); } while (0)

__global__ __launch_bounds__(512, 2) void gemm8(
    const unsigned short* __restrict__ A,   // GM x GK bf16
    const unsigned short* __restrict__ Bm,  // DD x GK bf16 (W row-major)
    const float* __restrict__ bias,         // DD fp32
    float* __restrict__ out) {
  __shared__ unsigned short lds[65536];     // 128 KiB

  // bijective XCD swizzle: 1024 wgs, 8 XCDs -> 128 contiguous per XCD
  int g = blockIdx.x;
  int t = ((g & 7) << 7) + (g >> 3);
  int mt = t >> 2, nt = t & 3;              // 256 M-tiles x 4 N-tiles
  int m0 = mt << 8, n0 = nt << 8;

  int tid = threadIdx.x, lane = tid & 63, wv = tid >> 6;
  int wm = wv >> 2, wn = wv & 3;            // 2M x 4N waves, each owns 128x64
  int fr = lane & 15, kg = lane >> 4;
  int sw = (fr & 7) << 3;                   // read-side swizzle (short idx)

  int srq = (wv << 3) + (lane >> 3);        // staging row within quarter
  int ssc = (((lane & 7) ^ ((lane >> 3) & 7)) << 3);  // pre-swizzled src col

  const unsigned short* Ag = A + (size_t)m0 * GK;
  const unsigned short* Bg = Bm + (size_t)n0 * GK;

  f32x4 acc[8][4] = {};
  bf16x8 ar[8], br[8];

  // ---- prologue: tile0 (8q) + tile1 {Aq0,Aq2,Bq0-3}; force tile0 ----
  {
    const unsigned short* b0 = Bg;
    const unsigned short* a1 = Ag + 64;
    const unsigned short* b1 = Bg + 64;
    STAGEQ(Ag, 0, 0); STAGEQ(Ag, 0, 1); STAGEQ(Ag, 0, 2); STAGEQ(Ag, 0, 3);
    STAGEQ(b0, 16384, 0); STAGEQ(b0, 16384, 1);
    STAGEQ(b0, 16384, 2); STAGEQ(b0, 16384, 3);
    STAGEQ(a1, 32768, 0); STAGEQ(a1, 32768, 2);
    STAGEQ(b1, 49152, 0); STAGEQ(b1, 49152, 1);
    STAGEQ(b1, 49152, 2); STAGEQ(b1, 49152, 3);
    asm volatile("s_waitcnt vmcnt(6)" ::: "memory");
    __builtin_amdgcn_sched_barrier(0);
    __builtin_amdgcn_s_barrier();
  }

  for (int i = 0; i < 7; ++i) {
    const unsigned short* a1 = Ag + (size_t)(2 * i + 1) * 64;
    const unsigned short* a2 = Ag + (size_t)(2 * i + 2) * 64;
    const unsigned short* b2 = Bg + (size_t)(2 * i + 2) * 64;
    const unsigned short* a3 = Ag + (size_t)(2 * i + 3) * 64;
    const unsigned short* b3 = Bg + (size_t)(2 * i + 3) * 64;
    // ph1: Q0 of tile 2i (buf0)
    LDA8(0, 0); LDB4(0, 16384);
    STAGEQ(a1, 32768, 1); STAGEQ(a1, 32768, 3);
    PH_MID; MFMAQ(0, 0); PH_END;
    // ph2: Q1
    LDB4(1, 16384);
    STAGEQ(a2, 0, 0); STAGEQ(a2, 0, 2);
    PH_MID; MFMAQ(0, 1); PH_END;
    // ph3: Q2
    LDA8(1, 0);
    STAGEQ(b2, 16384, 0); STAGEQ(b2, 16384, 1);
    PH_MID; MFMAQ(1, 0); PH_END;
    // ph4: Q3 (+vmcnt: forces tile 2i+1 complete)
    STAGEQ(b2, 16384, 2); STAGEQ(b2, 16384, 3);
    PH_MID; MFMAQ(1, 1); PH_END_V(6);
    // ph5: Q0 of tile 2i+1 (buf1)
    LDA8(0, 32768); LDB4(0, 49152);
    STAGEQ(a2, 0, 1); STAGEQ(a2, 0, 3);
    PH_MID; MFMAQ(0, 0); PH_END;
    // ph6: Q1
    LDB4(1, 49152);
    STAGEQ(a3, 32768, 0); STAGEQ(a3, 32768, 2);
    PH_MID; MFMAQ(0, 1); PH_END;
    // ph7: Q2
    LDA8(1, 32768);
    STAGEQ(b3, 49152, 0); STAGEQ(b3, 49152, 1);
    PH_MID; MFMAQ(1, 0); PH_END;
    // ph8: Q3 (+vmcnt: forces tile 2i+2 complete)
    STAGEQ(b3, 49152, 2); STAGEQ(b3, 49152, 3);
    PH_MID; MFMAQ(1, 1); PH_END_V(6);
  }

  // ---- peeled final iteration: tiles 14 (buf0), 15 (buf1) ----
  {
    const unsigned short* a15 = Ag + (size_t)15 * 64;
    LDA8(0, 0); LDB4(0, 16384);
    STAGEQ(a15, 32768, 1); STAGEQ(a15, 32768, 3);
    PH_MID; MFMAQ(0, 0); PH_END;
    LDB4(1, 16384); PH_MID; MFMAQ(0, 1); PH_END;
    LDA8(1, 0);     PH_MID; MFMAQ(1, 0); PH_END;
    PH_MID; MFMAQ(1, 1); PH_END_V(0);
    LDA8(0, 32768); LDB4(0, 49152); PH_MID; MFMAQ(0, 0); PH_END;
    LDB4(1, 49152); PH_MID; MFMAQ(0, 1); PH_END;
    LDA8(1, 32768); PH_MID; MFMAQ(1, 0); PH_END;
    PH_MID; MFMAQ(1, 1);
    __builtin_amdgcn_s_setprio(0);
  }

  // ---- epilogue: C/D layout col=lane&15, row=(lane>>4)*4+j ----
  int r0 = kg << 2, cc = fr;
#pragma unroll
  for (int ni = 0; ni < 4; ++ni) {
    int gcol = n0 + (wn << 6) + (ni << 4) + cc;
    float bv = bias[gcol];
#pragma unroll
    for (int mi = 0; mi < 8; ++mi) {
      int gr = m0 + (wm << 7) + (mi << 4) + r0;
#pragma unroll
      for (int j = 0; j < 4; ++j) {
        int grow = gr + j;                       // m index = b*4096 + s
        size_t o = ((size_t)(grow + (grow >> 12)) << 10) + gcol;
        out[o] = acc[mi][ni][j] + bv;
      }
    }
  }
}

// ---------------- final argmax reduce + token gather + l2norm ---------------
__global__ __launch_bounds__(256) void select_write(
    const float* __restrict__ pscore, const int* __restrict__ pidx, int nb,
    const int* __restrict__ ktv, const float* __restrict__ values,
    float* __restrict__ out) {
  __shared__ float ss[4];
  __shared__ int si[4];
  __shared__ float snrm;
  __shared__ int swin;
  int b = blockIdx.x, tid = threadIdx.x, lane = tid & 63, wv = tid >> 6;

  float best = -1e30f;
  int bidx = 0x7fffffff;
  for (int t = tid; t < nb; t += 256) {
    float s = pscore[(size_t)b * nb + t];
    int i = pidx[(size_t)b * nb + t];
    if (s > best || (s == best && i < bidx)) { best = s; bidx = i; }
  }
#pragma unroll
  for (int off = 32; off; off >>= 1) {
    float s = __shfl_xor(best, off);
    int i = __shfl_xor(bidx, off);
    if (s > best || (s == best && i < bidx)) { best = s; bidx = i; }
  }
  if (lane == 0) { ss[wv] = best; si[wv] = bidx; }
  __syncthreads();
  if (tid == 0) {
    float bs = ss[0]; int bi = si[0];
    for (int w2 = 1; w2 < 4; ++w2)
      if (ss[w2] > bs || (ss[w2] == bs && si[w2] < bi)) { bs = ss[w2]; bi = si[w2]; }
    swin = ktv[bi];   // key_to_value mapping
  }
  __syncthreads();
  int idx = swin;

  float4 v = ((const float4*)(values + (size_t)idx * DD))[tid];
  float nrm = v.x * v.x + v.y * v.y + v.z * v.z + v.w * v.w;
#pragma unroll
  for (int off = 32; off; off >>= 1) nrm += __shfl_xor(nrm, off);
  if (lane == 0) ss[wv] = nrm;
  __syncthreads();
  if (tid == 0) snrm = rsqrtf(fmaxf(ss[0] + ss[1] + ss[2] + ss[3], 1e-24f));
  __syncthreads();
  float inv = snrm;

  float4 o;
  o.x = v.x * inv; o.y = v.y * inv; o.z = v.z * inv; o.w = v.w * inv;
  ((float4*)(out + (((size_t)b * (SS + 1) + SS) << 10)))[tid] = o;
}

// ---------------- launcher ---------------------------------------------------
extern "C" void kernel_launch(void* const* d_in, const int* in_sizes, int n_in,
                              void* d_out, int out_size, void* d_ws,
                              size_t ws_size, hipStream_t stream) {
  const float* hidden = (const float*)d_in[0];
  const float* csig   = (const float*)d_in[1];
  const float* keys   = (const float*)d_in[2];
  const float* values = (const float*)d_in[3];
  const int*   ktv    = (const int*)d_in[4];
  const float* W      = (const float*)d_in[5];
  const float* bias   = (const float*)d_in[6];
  float* out = (float*)d_out;

  char* ws = (char*)d_ws;
  const size_t HB = (size_t)GM * GK * 2;        // 128 MB  bf16 hidden
  const size_t WB = (size_t)DD * GK * 2;        // 2 MB    bf16 W
  const size_t QB = (size_t)BB * DD * 2;        // 32 KB   qh / ql each
  const size_t PSB = (size_t)BB * 1024 * 4;     // 64 KB   pscore / pidx each

  unsigned short* hbf = (unsigned short*)ws;
  unsigned short* wbf = (unsigned short*)(ws + HB);
  unsigned short* qh  = (unsigned short*)(ws + HB + WB);
  unsigned short* ql  = (unsigned short*)(ws + HB + WB + QB);
  float* pscore = (float*)(ws + HB + WB + 2 * QB);
  int*   pidx   = (int*)(ws + HB + WB + 2 * QB + PSB);

  // 1) q hi/lo split (tiny)
  qsplit<<<64, 256, 0, stream>>>(csig, qh, ql);

  // 2) fused: cos scores/argmax + hidden->bf16 + W->bf16 (role-striped)
  fused_prep<<<5632, 256, 0, stream>>>(keys, qh, ql, pscore, pidx,
                                       hidden, hbf, W, wbf);

  // 3) GEMM + bias into out rows s<4096 (256^2 8-phase)
  gemm8<<<1024, 512, 0, stream>>>(hbf, wbf, bias, out);

  // 4) final reduce + token row s=4096
  select_write<<<BB, 256, 0, stream>>>(pscore, pidx, 1024, ktv, values, out);
}

// Round 9
// 374.428 us; speedup vs baseline: 1.0162x; 1.0162x over previous
//
#include <hip/hip_runtime.h>

// Problem constants (fixed by setup_inputs)
constexpr int BB = 16;         // batch
constexpr int SS = 4096;       // seq
constexpr int DD = 1024;       // hidden dim
constexpr int KK = 65536;      // num keys
constexpr int GM = BB * SS;    // GEMM M = 65536
constexpr int GK = DD;         // GEMM K = 1024

typedef __attribute__((ext_vector_type(8))) short bf16x8;
typedef __attribute__((ext_vector_type(4))) float f32x4;
typedef __attribute__((ext_vector_type(8))) unsigned short ushort8;

#define GLD_LDS16(g, l)                                                        \
  __builtin_amdgcn_global_load_lds(                                            \
      (const __attribute__((address_space(1))) void*)(g),                      \
      (__attribute__((address_space(3))) void*)(l), 16, 0, 0)

__device__ __forceinline__ unsigned short f2bf(float x) {
  unsigned u = __float_as_uint(x);
  u += 0x7fffu + ((u >> 16) & 1u);   // RNE
  return (unsigned short)(u >> 16);
}

// ---------------- cvt body: one float8 chunk ---------------------------------
__device__ __forceinline__ void cvt_body(const float* __restrict__ in,
                                         unsigned short* __restrict__ out,
                                         int i) {
  const float4* p = (const float4*)in + (size_t)i * 2;
  float4 a = p[0], b = p[1];
  ushort8 r;
  r[0] = f2bf(a.x); r[1] = f2bf(a.y); r[2] = f2bf(a.z); r[3] = f2bf(a.w);
  r[4] = f2bf(b.x); r[5] = f2bf(b.y); r[6] = f2bf(b.z); r[7] = f2bf(b.w);
  *(ushort8*)(out + (size_t)i * 8) = r;
}

// ---------------- q split: csig -> bf16 hi + bf16 lo residual ---------------
__global__ __launch_bounds__(256) void qsplit(const float* __restrict__ csig,
                                              unsigned short* __restrict__ qh,
                                              unsigned short* __restrict__ ql) {
  int i = blockIdx.x * 256 + threadIdx.x;   // 64 blocks cover 16384
  float v = csig[i];
  unsigned short h = f2bf(v);
  float hf = __uint_as_float((unsigned)h << 16);
  qh[i] = h;
  ql[i] = f2bf(v - hf);
}

// ---------------- cos scores via split-bf16 MFMA, depth-4 pipeline ----------
// Wave handles 16 keys (cols), all 16 batches.  Lane (fr,kg): key = base+fr,
// reads 32B of its key row at d = t*32 + kg*8.  Keys split in-register to
// bf16 hi/lo; dot = qh*kh + ql*kh + qh*kl (3 MFMA, err ~2^-18 << top-2 gap
// ~0.0076).  Norm exact fp32.  No LDS staging.
// Depth-4 slot rotation (static indices, rule #20): compute slot s while
// prefetching t+3 -> up to 12 outstanding loads/wave hides ~900cy HBM lat.
__device__ __forceinline__ void cos_mfma_body(
    const float* __restrict__ keys, const unsigned short* __restrict__ qh,
    const unsigned short* __restrict__ ql, float* __restrict__ pscore,
    int* __restrict__ pidx, int cblk, int tid,
    float (*rs)[16], int (*ri)[16]) {
  int lane = tid & 63, w = tid >> 6;
  int fr = lane & 15, kg = lane >> 4;
  int key = cblk * 64 + w * 16 + fr;

  const float* krow = keys + (size_t)key * DD + kg * 8;
  const unsigned short* qhp = qh + fr * DD + kg * 8;
  const unsigned short* qlp = ql + fr * DD + kg * 8;

  f32x4 acc = {};
  float nrm = 0.f;

  float4 ka0, kb0, ka1, kb1, ka2, kb2, ka3, kb3;
  bf16x8 h0, l0, h1, l1, h2, l2, h3, l3;

  // preload t = 0,1,2 into slots 0,1,2
  ka0 = *(const float4*)(krow);      kb0 = *(const float4*)(krow + 4);
  h0  = *(const bf16x8*)(qhp);       l0  = *(const bf16x8*)(qlp);
  ka1 = *(const float4*)(krow + 32); kb1 = *(const float4*)(krow + 36);
  h1  = *(const bf16x8*)(qhp + 32);  l1  = *(const bf16x8*)(qlp + 32);
  ka2 = *(const float4*)(krow + 64); kb2 = *(const float4*)(krow + 68);
  h2  = *(const bf16x8*)(qhp + 64);  l2  = *(const bf16x8*)(qlp + 64);

#define COS_STEP(KA, KB, HH, LL, KAP, KBP, HP, LP, T) do {                     \
    if ((T) + 3 < 32) {                                                        \
      KAP = *(const float4*)(krow + ((T) + 3) * 32);                           \
      KBP = *(const float4*)(krow + ((T) + 3) * 32 + 4);                       \
      HP  = *(const bf16x8*)(qhp + ((T) + 3) * 32);                            \
      LP  = *(const bf16x8*)(qlp + ((T) + 3) * 32);                            \
    }                                                                          \
    float ke[8] = {KA.x, KA.y, KA.z, KA.w, KB.x, KB.y, KB.z, KB.w};            \
    ushort8 khv, klv;                                                          \
    _Pragma("unroll") for (int j = 0; j < 8; ++j) {                            \
      float v = ke[j];                                                         \
      unsigned short h = f2bf(v);                                              \
      float hf = __uint_as_float((unsigned)h << 16);                           \
      khv[j] = h;                                                              \
      klv[j] = f2bf(v - hf);                                                   \
      nrm = fmaf(v, v, nrm);                                                   \
    }                                                                          \
    bf16x8 kh8 = *(bf16x8*)&khv, kl8 = *(bf16x8*)&klv;                         \
    acc = __builtin_amdgcn_mfma_f32_16x16x32_bf16(HH, kh8, acc, 0, 0, 0);      \
    acc = __builtin_amdgcn_mfma_f32_16x16x32_bf16(LL, kh8, acc, 0, 0, 0);      \
    acc = __builtin_amdgcn_mfma_f32_16x16x32_bf16(HH, kl8, acc, 0, 0, 0);      \
  } while (0)

#pragma unroll
  for (int tt = 0; tt < 32; tt += 4) {
    COS_STEP(ka0, kb0, h0, l0, ka3, kb3, h3, l3, tt + 0);
    COS_STEP(ka1, kb1, h1, l1, ka0, kb0, h0, l0, tt + 1);
    COS_STEP(ka2, kb2, h2, l2, ka1, kb1, h1, l1, tt + 2);
    COS_STEP(ka3, kb3, h3, l3, ka2, kb2, h2, l2, tt + 3);
  }
#undef COS_STEP

  // full ||k||^2: reduce across the 4 kg-lanes of this key
  nrm += __shfl_xor(nrm, 16);
  nrm += __shfl_xor(nrm, 32);
  float inv = rsqrtf(fmaxf(nrm, 1e-24f));

  // lane holds batches kg*4+j for its key; argmax over fr within wave
#pragma unroll
  for (int j = 0; j < 4; ++j) {
    float s = acc[j] * inv;
    int i = key;
#pragma unroll
    for (int off = 1; off < 16; off <<= 1) {
      float s2 = __shfl_xor(s, off);
      int i2 = __shfl_xor(i, off);
      if (s2 > s || (s2 == s && i2 < i)) { s = s2; i = i2; }
    }
    if (fr == 0) { rs[w][kg * 4 + j] = s; ri[w][kg * 4 + j] = i; }
  }
  __syncthreads();
  if (tid < 16) {
    float bs = rs[0][tid]; int bi = ri[0][tid];
#pragma unroll
    for (int w2 = 1; w2 < 4; ++w2) {
      float s = rs[w2][tid]; int i = ri[w2][tid];
      if (s > bs || (s == bs && i < bi)) { bs = s; bi = i; }
    }
    pscore[(size_t)tid * 1024 + cblk] = bs;
    pidx[(size_t)tid * 1024 + cblk] = bi;
  }
}

// ---------------- fused prep: cos + cvt(hidden) + cvt(W), role-striped ------
// 5632 blocks = 512 stripes x 11 (2 cos + 9 cvt) -> cos and cvt co-resident
// on every CU from dispatch start; cvt waves' loads hide cos's HBM latency.
__global__ __launch_bounds__(256) void fused_prep(
    const float* __restrict__ keys, const unsigned short* __restrict__ qh,
    const unsigned short* __restrict__ ql, float* __restrict__ pscore,
    int* __restrict__ pidx,
    const float* __restrict__ hidden, unsigned short* __restrict__ hbf,
    const float* __restrict__ W, unsigned short* __restrict__ wbf) {
  __shared__ float rs[4][16];
  __shared__ int ri[4][16];
  int bid = blockIdx.x, tid = threadIdx.x;
  int g = bid / 11, r = bid - g * 11;
  if (r < 2) {
    cos_mfma_body(keys, qh, ql, pscore, pidx, g * 2 + r, tid, rs, ri);
  } else {
    int v = g * 9 + (r - 2);         // 0..4607
    if (v < 4096) {
      // hidden: 8388608 chunks = 4096 v-slots x 256 thr x 8 rounds
      int base = v * 256 + tid;
#pragma unroll
      for (int q = 0; q < 8; ++q)
        cvt_body(hidden, hbf, base + q * (4096 * 256));
    } else {
      // W: 131072 chunks = 512 v-slots x 256 thr
      cvt_body(W, wbf, (v - 4096) * 256 + tid);
    }
  }
}

// =====================  GEMM: 256x256 tile, 8-phase (R3-proven) =============
// C[m,n] = sum_k A[m,k]*W[n,k] + bias[n].  BM=BN=256, BK=64, 8 waves (2Mx4N),
// LDS 128 KiB (2 buf x (A 32KB + B 32KB)).  K = 1024 -> 16 K-tiles, 8 iters.
// vmcnt(6) at ph4/ph8 forces next tile fully landed before its first read.
// LDS swizzle: short_idx ^= (row&7)<<3, applied as inverse-permuted GLOBAL
// source + swizzled ds_read (both-sides rule).

#define LDA8(AH, BUF) do {                                                     \
  _Pragma("unroll") for (int ms = 0; ms < 4; ++ms) {                           \
    int rowa = (wm << 7) + ((AH) << 6) + (ms << 4) + fr;                       \
    _Pragma("unroll") for (int ks = 0; ks < 2; ++ks) {                         \
      int ia = ((rowa << 6) + (ks << 5) + (kg << 3)) ^ sw;                     \
      ar[ms * 2 + ks] = *(const bf16x8*)&lds[(BUF) + ia]; } }                  \
} while (0)

#define LDB4(NP, BUF) do {                                                     \
  _Pragma("unroll") for (int nn = 0; nn < 2; ++nn) {                           \
    int rowb = (wn << 6) + ((((NP) << 1) + nn) << 4) + fr;                     \
    _Pragma("unroll") for (int ks = 0; ks < 2; ++ks) {                         \
      int ib = ((rowb << 6) + (ks << 5) + (kg << 3)) ^ sw;                     \
      br[(((NP) << 1) + nn) * 2 + ks] = *(const bf16x8*)&lds[(BUF) + ib]; } }  \
} while (0)

#define MFMAQ(AH, NP) do {                                                     \
  _Pragma("unroll") for (int ms = 0; ms < 4; ++ms)                             \
  _Pragma("unroll") for (int nn = 0; nn < 2; ++nn)                             \
  _Pragma("unroll") for (int ks = 0; ks < 2; ++ks)                             \
    acc[((AH) << 2) + ms][((NP) << 1) + nn] =                                  \
      __builtin_amdgcn_mfma_f32_16x16x32_bf16(ar[ms * 2 + ks],                 \
        br[(((NP) << 1) + nn) * 2 + ks],                                       \
        acc[((AH) << 2) + ms][((NP) << 1) + nn], 0, 0, 0);                     \
} while (0)

#define STAGEQ(GB, LB, QJ)                                                     \
  GLD_LDS16((GB) + (size_t)(((QJ) << 6) + srq) * GK + ssc,                     \
            &lds[(LB) + ((((QJ) << 9) + (wv << 6)) << 3)])

#define PH_MID do { __builtin_amdgcn_s_barrier();                              \
  asm volatile("s_waitcnt lgkmcnt(0)" ::: "memory");                           \
  __builtin_amdgcn_sched_barrier(0);                                           \
  __builtin_amdgcn_s_setprio(1); } while (0)

#define PH_END do { __builtin_amdgcn_s_setprio(0);                             \
  __builtin_amdgcn_s_barrier(); } while (0)

#define PH_END_V(N) do { __builtin_amdgcn_s_setprio(0);                        \
  asm volatile("s_waitcnt vmcnt(" #N ")" ::: "memory");                        \
  __builtin_amdgcn_sched_barrier(0);                                           \
  __builtin_amdgcn_s_barrier(); } while (0)

__global__ __launch_bounds__(512, 2) void gemm8(
    const unsigned short* __restrict__ A,   // GM x GK bf16
    const unsigned short* __restrict__ Bm,  // DD x GK bf16 (W row-major)
    const float* __restrict__ bias,         // DD fp32
    float* __restrict__ out) {
  __shared__ unsigned short lds[65536];     // 128 KiB

  // bijective XCD swizzle: 1024 wgs, 8 XCDs -> 128 contiguous per XCD
  int g = blockIdx.x;
  int t = ((g & 7) << 7) + (g >> 3);
  int mt = t >> 2, nt = t & 3;              // 256 M-tiles x 4 N-tiles
  int m0 = mt << 8, n0 = nt << 8;

  int tid = threadIdx.x, lane = tid & 63, wv = tid >> 6;
  int wm = wv >> 2, wn = wv & 3;            // 2M x 4N waves, each owns 128x64
  int fr = lane & 15, kg = lane >> 4;
  int sw = (fr & 7) << 3;                   // read-side swizzle (short idx)

  int srq = (wv << 3) + (lane >> 3);        // staging row within quarter
  int ssc = (((lane & 7) ^ ((lane >> 3) & 7)) << 3);  // pre-swizzled src col

  const unsigned short* Ag = A + (size_t)m0 * GK;
  const unsigned short* Bg = Bm + (size_t)n0 * GK;

  f32x4 acc[8][4] = {};
  bf16x8 ar[8], br[8];

  // ---- prologue: tile0 (8q) + tile1 {Aq0,Aq2,Bq0-3}; force tile0 ----
  {
    const unsigned short* b0 = Bg;
    const unsigned short* a1 = Ag + 64;
    const unsigned short* b1 = Bg + 64;
    STAGEQ(Ag, 0, 0); STAGEQ(Ag, 0, 1); STAGEQ(Ag, 0, 2); STAGEQ(Ag, 0, 3);
    STAGEQ(b0, 16384, 0); STAGEQ(b0, 16384, 1);
    STAGEQ(b0, 16384, 2); STAGEQ(b0, 16384, 3);
    STAGEQ(a1, 32768, 0); STAGEQ(a1, 32768, 2);
    STAGEQ(b1, 49152, 0); STAGEQ(b1, 49152, 1);
    STAGEQ(b1, 49152, 2); STAGEQ(b1, 49152, 3);
    asm volatile("s_waitcnt vmcnt(6)" ::: "memory");
    __builtin_amdgcn_sched_barrier(0);
    __builtin_amdgcn_s_barrier();
  }

  for (int i = 0; i < 7; ++i) {
    const unsigned short* a1 = Ag + (size_t)(2 * i + 1) * 64;
    const unsigned short* a2 = Ag + (size_t)(2 * i + 2) * 64;
    const unsigned short* b2 = Bg + (size_t)(2 * i + 2) * 64;
    const unsigned short* a3 = Ag + (size_t)(2 * i + 3) * 64;
    const unsigned short* b3 = Bg + (size_t)(2 * i + 3) * 64;
    // ph1: Q0 of tile 2i (buf0)
    LDA8(0, 0); LDB4(0, 16384);
    STAGEQ(a1, 32768, 1); STAGEQ(a1, 32768, 3);
    PH_MID; MFMAQ(0, 0); PH_END;
    // ph2: Q1
    LDB4(1, 16384);
    STAGEQ(a2, 0, 0); STAGEQ(a2, 0, 2);
    PH_MID; MFMAQ(0, 1); PH_END;
    // ph3: Q2
    LDA8(1, 0);
    STAGEQ(b2, 16384, 0); STAGEQ(b2, 16384, 1);
    PH_MID; MFMAQ(1, 0); PH_END;
    // ph4: Q3 (+vmcnt: forces tile 2i+1 complete)
    STAGEQ(b2, 16384, 2); STAGEQ(b2, 16384, 3);
    PH_MID; MFMAQ(1, 1); PH_END_V(6);
    // ph5: Q0 of tile 2i+1 (buf1)
    LDA8(0, 32768); LDB4(0, 49152);
    STAGEQ(a2, 0, 1); STAGEQ(a2, 0, 3);
    PH_MID; MFMAQ(0, 0); PH_END;
    // ph6: Q1
    LDB4(1, 49152);
    STAGEQ(a3, 32768, 0); STAGEQ(a3, 32768, 2);
    PH_MID; MFMAQ(0, 1); PH_END;
    // ph7: Q2
    LDA8(1, 32768);
    STAGEQ(b3, 49152, 0); STAGEQ(b3, 49152, 1);
    PH_MID; MFMAQ(1, 0); PH_END;
    // ph8: Q3 (+vmcnt: forces tile 2i+2 complete)
    STAGEQ(b3, 49152, 2); STAGEQ(b3, 49152, 3);
    PH_MID; MFMAQ(1, 1); PH_END_V(6);
  }

  // ---- peeled final iteration: tiles 14 (buf0), 15 (buf1) ----
  {
    const unsigned short* a15 = Ag + (size_t)15 * 64;
    LDA8(0, 0); LDB4(0, 16384);
    STAGEQ(a15, 32768, 1); STAGEQ(a15, 32768, 3);
    PH_MID; MFMAQ(0, 0); PH_END;
    LDB4(1, 16384); PH_MID; MFMAQ(0, 1); PH_END;
    LDA8(1, 0);     PH_MID; MFMAQ(1, 0); PH_END;
    PH_MID; MFMAQ(1, 1); PH_END_V(0);
    LDA8(0, 32768); LDB4(0, 49152); PH_MID; MFMAQ(0, 0); PH_END;
    LDB4(1, 49152); PH_MID; MFMAQ(0, 1); PH_END;
    LDA8(1, 32768); PH_MID; MFMAQ(1, 0); PH_END;
    PH_MID; MFMAQ(1, 1);
    __builtin_amdgcn_s_setprio(0);
  }

  // ---- epilogue: C/D layout col=lane&15, row=(lane>>4)*4+j ----
  int r0 = kg << 2, cc = fr;
#pragma unroll
  for (int ni = 0; ni < 4; ++ni) {
    int gcol = n0 + (wn << 6) + (ni << 4) + cc;
    float bv = bias[gcol];
#pragma unroll
    for (int mi = 0; mi < 8; ++mi) {
      int gr = m0 + (wm << 7) + (mi << 4) + r0;
#pragma unroll
      for (int j = 0; j < 4; ++j) {
        int grow = gr + j;                       // m index = b*4096 + s
        size_t o = ((size_t)(grow + (grow >> 12)) << 10) + gcol;
        out[o] = acc[mi][ni][j] + bv;
      }
    }
  }
}

// ---------------- final argmax reduce + token gather + l2norm ---------------
__global__ __launch_bounds__(256) void select_write(
    const float* __restrict__ pscore, const int* __restrict__ pidx, int nb,
    const int* __restrict__ ktv, const float* __restrict__ values,
    float* __restrict__ out) {
  __shared__ float ss[4];
  __shared__ int si[4];
  __shared__ float snrm;
  __shared__ int swin;
  int b = blockIdx.x, tid = threadIdx.x, lane = tid & 63, wv = tid >> 6;

  float best = -1e30f;
  int bidx = 0x7fffffff;
  for (int t = tid; t < nb; t += 256) {
    float s = pscore[(size_t)b * nb + t];
    int i = pidx[(size_t)b * nb + t];
    if (s > best || (s == best && i < bidx)) { best = s; bidx = i; }
  }
#pragma unroll
  for (int off = 32; off; off >>= 1) {
    float s = __shfl_xor(best, off);
    int i = __shfl_xor(bidx, off);
    if (s > best || (s == best && i < bidx)) { best = s; bidx = i; }
  }
  if (lane == 0) { ss[wv] = best; si[wv] = bidx; }
  __syncthreads();
  if (tid == 0) {
    float bs = ss[0]; int bi = si[0];
    for (int w2 = 1; w2 < 4; ++w2)
      if (ss[w2] > bs || (ss[w2] == bs && si[w2] < bi)) { bs = ss[w2]; bi = si[w2]; }
    swin = ktv[bi];   // key_to_value mapping
  }
  __syncthreads();
  int idx = swin;

  float4 v = ((const float4*)(values + (size_t)idx * DD))[tid];
  float nrm = v.x * v.x + v.y * v.y + v.z * v.z + v.w * v.w;
#pragma unroll
  for (int off = 32; off; off >>= 1) nrm += __shfl_xor(nrm, off);
  if (lane == 0) ss[wv] = nrm;
  __syncthreads();
  if (tid == 0) snrm = rsqrtf(fmaxf(ss[0] + ss[1] + ss[2] + ss[3], 1e-24f));
  __syncthreads();
  float inv = snrm;

  float4 o;
  o.x = v.x * inv; o.y = v.y * inv; o.z = v.z * inv; o.w = v.w * inv;
  ((float4*)(out + (((size_t)b * (SS + 1) + SS) << 10)))[tid] = o;
}

// ---------------- launcher ---------------------------------------------------
extern "C" void kernel_launch(void* const* d_in, const int* in_sizes, int n_in,
                              void* d_out, int out_size, void* d_ws,
                              size_t ws_size, hipStream_t stream) {
  const float* hidden = (const float*)d_in[0];
  const float* csig   = (const float*)d_in[1];
  const float* keys   = (const float*)d_in[2];
  const float* values = (const float*)d_in[3];
  const int*   ktv    = (const int*)d_in[4];
  const float* W      = (const float*)d_in[5];
  const float* bias   = (const float*)d_in[6];
  float* out = (float*)d_out;

  char* ws = (char*)d_ws;
  const size_t HB = (size_t)GM * GK * 2;        // 128 MB  bf16 hidden
  const size_t WB = (size_t)DD * GK * 2;        // 2 MB    bf16 W
  const size_t QB = (size_t)BB * DD * 2;        // 32 KB   qh / ql each
  const size_t PSB = (size_t)BB * 1024 * 4;     // 64 KB   pscore / pidx each

  unsigned short* hbf = (unsigned short*)ws;
  unsigned short* wbf = (unsigned short*)(ws + HB);
  unsigned short* qh  = (unsigned short*)(ws + HB + WB);
  unsigned short* ql  = (unsigned short*)(ws + HB + WB + QB);
  float* pscore = (float*)(ws + HB + WB + 2 * QB);
  int*   pidx   = (int*)(ws + HB + WB + 2 * QB + PSB);

  // 1) q hi/lo split (tiny)
  qsplit<<<64, 256, 0, stream>>>(csig, qh, ql);

  // 2) fused: cos scores/argmax + hidden->bf16 + W->bf16 (role-striped)
  fused_prep<<<5632, 256, 0, stream>>>(keys, qh, ql, pscore, pidx,
                                       hidden, hbf, W, wbf);

  // 3) GEMM + bias into out rows s<4096 (256^2 8-phase)
  gemm8<<<1024, 512, 0, stream>>>(hbf, wbf, bias, out);

  // 4) final reduce + token row s=4096
  select_write<<<BB, 256, 0, stream>>>(pscore, pidx, 1024, ktv, values, out);
}